// Round 3
// baseline (315.085 us; speedup 1.0000x reference)
//
#include <hip/hip_runtime.h>
#include <hip/hip_bf16.h>

#define NWAVE 16
#define MAXN 64

constexpr float PI_OVER_CUT = 3.14159265358979323846f / 5.0f;

// ======================= padded-CSR fused preprocess =======================
// One thread per neighbor: rank via atomicAdd, geometry, single packed float4
// write at i0*MAXN+rank.  w = dist with low 2 mantissa bits = species.

__global__ __launch_bounds__(256) void prep_padded(
    const float* __restrict__ cart, const int* __restrict__ idx0,
    const int* __restrict__ idx1, const int* __restrict__ nspec,
    unsigned* __restrict__ counts, float4* __restrict__ geomP, int nneigh)
{
    int j = blockIdx.x * blockDim.x + threadIdx.x;
    if (j >= nneigh) return;
    int i0 = idx0[j], i1 = idx1[j], s = nspec[j];
    float ax = cart[3*i0], ay = cart[3*i0+1], az = cart[3*i0+2];
    float bx = cart[3*i1], by = cart[3*i1+1], bz = cart[3*i1+2];
    float dxv = ax - bx, dyv = ay - by, dzv = az - bz;
    float d2 = dxv*dxv + dyv*dyv + dzv*dzv;
    float rinv = rsqrtf(d2);
    float dist = d2 * rinv;
    unsigned db = (__float_as_uint(dist) & ~3u) | (unsigned)s;
    unsigned rank = atomicAdd(&counts[i0], 1u);
    if (rank < MAXN)
        geomP[(size_t)i0 * MAXN + rank] =
            make_float4(dxv * rinv, dyv * rinv, dzv * rinv, __uint_as_float(db));
}

// ======================= density: one wave per atom, padded rows =======================
// lane = g*16 + k.  k = radial channel, g = angular group:
//   g=0: comps {0, xx, yy, zz}   g=1: {x, xy, yz}
//   g=2: {y, xz, zx}             g=3: {z, yx, zy}

__global__ __launch_bounds__(256) void density_pad(
    const float* __restrict__ rs, const float* __restrict__ inta,
    const float* __restrict__ params, const unsigned* __restrict__ counts,
    const float4* __restrict__ geomP, float* __restrict__ out, int nlocal)
{
    int t = threadIdx.x;
    int lane = t & 63;
    int k = lane & 15, g = lane >> 4;

    // per-lane radial constants for all 4 species (register-resident)
    float rs0 = rs[0*NWAVE+k], rs1 = rs[1*NWAVE+k], rs2 = rs[2*NWAVE+k], rs3 = rs[3*NWAVE+k];
    float ia0 = inta[0*NWAVE+k], ia1 = inta[1*NWAVE+k], ia2 = inta[2*NWAVE+k], ia3 = inta[3*NWAVE+k];
    float pp0 = params[0*NWAVE+k], pp1 = params[1*NWAVE+k], pp2 = params[2*NWAVE+k], pp3 = params[3*NWAVE+k];

    int a1, b1, a2, b2;
    switch (g) {
      case 0:  a1=0; b1=0; a2=1; b2=1; break;
      case 1:  a1=0; b1=1; a2=1; b2=2; break;
      case 2:  a1=0; b1=2; a2=2; b2=0; break;
      default: a1=1; b1=0; a2=2; b2=1; break;
    }
    float zsel = (g == 0) ? 1.f : 0.f;

    int wave = blockIdx.x * 4 + (t >> 6);
    int nwaves = gridDim.x * 4;

    for (int a = wave; a < nlocal; a += nwaves) {
        unsigned cnt = counts[a];
        if (cnt > MAXN) cnt = MAXN;
        const float4* row = geomP + (size_t)a * MAXN;

        float acc0 = 0.f, acc1 = 0.f, acc2 = 0.f, acc3 = 0.f;

        auto body = [&](float4 q) {
            unsigned u = __float_as_uint(q.w);
            bool c1 = (u & 1u) != 0u, c2 = (u & 2u) != 0u;
            float dist = __uint_as_float(u & ~3u);
            float rsel = c2 ? (c1 ? rs3 : rs2) : (c1 ? rs1 : rs0);
            float isel = c2 ? (c1 ? ia3 : ia2) : (c1 ? ia1 : ia0);
            float psel = c2 ? (c1 ? pp3 : pp2) : (c1 ? pp1 : pp0);
            float dd = dist - rsel;
            float rad = __expf(-isel * dd * dd);
            float fc = fmaf(0.5f, __cosf(dist * PI_OVER_CUT), 0.5f);
            float w = rad * (fc * fc) * psel;
            float dx = q.x, dy = q.y, dz = q.z;
            float f1 = (g == 0) ? 1.f : (g == 1 ? dx : (g == 2 ? dy : dz));
            acc0 = fmaf(f1, w, acc0);
            float pa1 = (a1 == 0 ? dx : (a1 == 1 ? dy : dz));
            float pb1 = (b1 == 0 ? dx : (b1 == 1 ? dy : dz));
            acc1 = fmaf(pa1 * pb1, w, acc1);
            float pa2 = (a2 == 0 ? dx : (a2 == 1 ? dy : dz));
            float pb2 = (b2 == 0 ? dx : (b2 == 1 ? dy : dz));
            acc2 = fmaf(pa2 * pb2, w, acc2);
            acc3 = fmaf(zsel * dz * dz, w, acc3);
        };

        unsigned i = 0;
        for (; i + 2 <= cnt; i += 2) {
            float4 q0 = row[i];
            float4 q1 = row[i + 1];
            body(q0);
            body(q1);
        }
        if (i < cnt) body(row[i]);

        float l0, l1, l2;
        if (g == 0) { l0 = acc0*acc0; l1 = 0.f;       l2 = acc1*acc1 + acc2*acc2 + acc3*acc3; }
        else        { l0 = 0.f;       l1 = acc0*acc0; l2 = acc1*acc1 + acc2*acc2; }
        l0 += __shfl_xor(l0, 16, 64); l1 += __shfl_xor(l1, 16, 64); l2 += __shfl_xor(l2, 16, 64);
        l0 += __shfl_xor(l0, 32, 64); l1 += __shfl_xor(l1, 32, 64); l2 += __shfl_xor(l2, 32, 64);

        if (g == 0) {
            out[a*48 + k]      = l0;
            out[a*48 + 16 + k] = l1;
            out[a*48 + 32 + k] = l2;
        }
    }
}

// ======================= fallback: R2 pipeline =======================

__global__ void hist_kernel(const int* __restrict__ idx0, unsigned* __restrict__ counts, int nneigh) {
    int j = blockIdx.x * blockDim.x + threadIdx.x;
    if (j < nneigh) atomicAdd(&counts[idx0[j]], 1u);
}

__global__ __launch_bounds__(256) void scan_partial(const unsigned* __restrict__ counts,
                                                    unsigned* __restrict__ partials, int n) {
    __shared__ unsigned wsum[4];
    int t = threadIdx.x;
    int base = blockIdx.x * 1024 + t * 4;
    unsigned s = 0;
    #pragma unroll
    for (int e = 0; e < 4; ++e) { int id = base + e; if (id < n) s += counts[id]; }
    #pragma unroll
    for (int off = 32; off >= 1; off >>= 1) s += __shfl_xor(s, off, 64);
    int lane = t & 63, w = t >> 6;
    if (lane == 0) wsum[w] = s;
    __syncthreads();
    if (t == 0) partials[blockIdx.x] = wsum[0] + wsum[1] + wsum[2] + wsum[3];
}

__global__ __launch_bounds__(64) void scan_blockoffs(const unsigned* __restrict__ partials,
                                                     unsigned* __restrict__ blockoff,
                                                     unsigned* __restrict__ offsets,
                                                     int nblk, int nlocal) {
    int t = threadIdx.x;
    unsigned v = (t < nblk) ? partials[t] : 0u;
    unsigned incl = v;
    #pragma unroll
    for (int off = 1; off < 64; off <<= 1) {
        unsigned u = __shfl_up(incl, off, 64);
        if (t >= off) incl += u;
    }
    if (t < nblk) blockoff[t] = incl - v;
    if (t == nblk - 1) offsets[nlocal] = incl;
}

__global__ __launch_bounds__(256) void scan_final(const unsigned* __restrict__ counts,
                                                  const unsigned* __restrict__ blockoff,
                                                  unsigned* __restrict__ offsets,
                                                  unsigned* __restrict__ cursor, int n) {
    __shared__ unsigned wsum[4];
    int t = threadIdx.x;
    int lane = t & 63, w = t >> 6;
    int base = blockIdx.x * 1024 + t * 4;
    unsigned c[4];
    #pragma unroll
    for (int e = 0; e < 4; ++e) { int id = base + e; c[e] = (id < n) ? counts[id] : 0u; }
    unsigned tsum = c[0] + c[1] + c[2] + c[3];
    unsigned incl = tsum;
    #pragma unroll
    for (int off = 1; off < 64; off <<= 1) {
        unsigned u = __shfl_up(incl, off, 64);
        if (lane >= off) incl += u;
    }
    if (lane == 63) wsum[w] = incl;
    __syncthreads();
    unsigned wpre = 0;
    for (int i = 0; i < 4; ++i) if (i < w) wpre += wsum[i];
    unsigned x = blockoff[blockIdx.x] + wpre + (incl - tsum);
    #pragma unroll
    for (int e = 0; e < 4; ++e) {
        int id = base + e;
        if (id < n) { offsets[id] = x; cursor[id] = x; }
        x += c[e];
    }
}

__global__ __launch_bounds__(256) void geom_scatter(
    const float* __restrict__ cart, const int* __restrict__ idx0,
    const int* __restrict__ idx1, const int* __restrict__ nspec,
    unsigned* __restrict__ cursor, float4* __restrict__ geomA,
    float2* __restrict__ geomB, int nneigh)
{
    int j = blockIdx.x * blockDim.x + threadIdx.x;
    if (j >= nneigh) return;
    int i0 = idx0[j], i1 = idx1[j], s = nspec[j];
    float ax = cart[3*i0], ay = cart[3*i0+1], az = cart[3*i0+2];
    float bx = cart[3*i1], by = cart[3*i1+1], bz = cart[3*i1+2];
    float dxv = ax - bx, dyv = ay - by, dzv = az - bz;
    float d2 = dxv*dxv + dyv*dyv + dzv*dzv;
    float rinv = rsqrtf(d2);
    float dist = d2 * rinv;
    float fc = 0.5f * __cosf(dist * PI_OVER_CUT) + 0.5f;
    float fcut = fc * fc;
    unsigned p = atomicAdd(&cursor[i0], 1u);
    geomA[p] = make_float4(dxv * rinv, dyv * rinv, dzv * rinv, dist);
    geomB[p] = make_float2(fcut, __int_as_float(s));
}

__global__ __launch_bounds__(256) void density_fast(
    const float* __restrict__ rs, const float* __restrict__ inta,
    const float* __restrict__ params, const unsigned* __restrict__ offsets,
    const float4* __restrict__ geomA, const float2* __restrict__ geomB,
    float* __restrict__ out, int nlocal)
{
    __shared__ float4 tab[64];
    int t = threadIdx.x;
    if (t < 64) {
        int s = t >> 4, k = t & 15;
        tab[t] = make_float4(rs[s*NWAVE + k], inta[s*NWAVE + k], params[s*NWAVE + k], 0.f);
    }
    __syncthreads();
    int a = blockIdx.x * 4 + (t >> 6);
    if (a >= nlocal) return;
    int lane = t & 63;
    int k = lane & 15, g = lane >> 4;
    int a1, b1, a2, b2;
    switch (g) {
      case 0:  a1=0; b1=0; a2=1; b2=1; break;
      case 1:  a1=0; b1=1; a2=1; b2=2; break;
      case 2:  a1=0; b1=2; a2=2; b2=0; break;
      default: a1=1; b1=0; a2=2; b2=1; break;
    }
    float acc0 = 0.f, acc1 = 0.f, acc2 = 0.f, acc3 = 0.f;
    unsigned beg = offsets[a], end = offsets[a + 1];
    for (unsigned n = beg; n < end; ++n) {
        float4 gA = geomA[n];
        float2 gB = geomB[n];
        int s = __float_as_int(gB.y);
        float4 tb = tab[s*NWAVE + k];
        float dd = gA.w - tb.x;
        float rad = __expf(-tb.y * dd * dd) * (gB.x * tb.z);
        float dx = gA.x, dy = gA.y, dz = gA.z;
        float f1 = (g == 0) ? 1.f : (g == 1 ? dx : (g == 2 ? dy : dz));
        acc0 = fmaf(f1, rad, acc0);
        float pa1 = (a1 == 0 ? dx : (a1 == 1 ? dy : dz));
        float pb1 = (b1 == 0 ? dx : (b1 == 1 ? dy : dz));
        acc1 = fmaf(pa1 * pb1, rad, acc1);
        float pa2 = (a2 == 0 ? dx : (a2 == 1 ? dy : dz));
        float pb2 = (b2 == 0 ? dx : (b2 == 1 ? dy : dz));
        acc2 = fmaf(pa2 * pb2, rad, acc2);
        if (g == 0) acc3 = fmaf(dz * dz, rad, acc3);
    }
    float l0, l1, l2;
    if (g == 0) { l0 = acc0*acc0; l1 = 0.f;       l2 = acc1*acc1 + acc2*acc2 + acc3*acc3; }
    else        { l0 = 0.f;       l1 = acc0*acc0; l2 = acc1*acc1 + acc2*acc2; }
    l0 += __shfl_xor(l0, 16, 64); l1 += __shfl_xor(l1, 16, 64); l2 += __shfl_xor(l2, 16, 64);
    l0 += __shfl_xor(l0, 32, 64); l1 += __shfl_xor(l1, 32, 64); l2 += __shfl_xor(l2, 32, 64);
    if (g == 0) {
        out[a*48 + k]      = l0;
        out[a*48 + 16 + k] = l1;
        out[a*48 + 32 + k] = l2;
    }
}

// ======================= launch =======================

extern "C" void kernel_launch(void* const* d_in, const int* in_sizes, int n_in,
                              void* d_out, int out_size, void* d_ws, size_t ws_size,
                              hipStream_t stream) {
    const float* cart   = (const float*)d_in[0];
    const float* rs     = (const float*)d_in[1];
    const float* inta   = (const float*)d_in[2];
    const float* params = (const float*)d_in[3];
    const int* atom_index    = (const int*)d_in[4];
    const int* neigh_species = (const int*)d_in[6];
    int nlocal = in_sizes[5];
    int nneigh = in_sizes[6];
    const int* idx0 = atom_index;
    const int* idx1 = atom_index + nneigh;

    int tb = 256;
    int nblkN = (nneigh + tb - 1) / tb;

    // ---- padded-CSR fast path ----
    {
        size_t off = 0;
        auto carve = [&](size_t bytes) -> size_t {
            off = (off + 255) & ~(size_t)255;
            size_t p = off; off += bytes; return p;
        };
        size_t counts_o = carve((size_t)nlocal * 4);
        size_t geomP_o  = carve((size_t)nlocal * MAXN * 16);
        if (ws_size >= off) {
            unsigned* counts = (unsigned*)((char*)d_ws + counts_o);
            float4*   geomP  = (float4*)((char*)d_ws + geomP_o);
            hipMemsetAsync(counts, 0, (size_t)nlocal * 4, stream);
            prep_padded<<<nblkN, tb, 0, stream>>>(cart, idx0, idx1, neigh_species,
                                                  counts, geomP, nneigh);
            density_pad<<<2048, 256, 0, stream>>>(rs, inta, params, counts, geomP,
                                                  (float*)d_out, nlocal);
            return;
        }
    }

    // ---- fallback: R2 pipeline ----
    char* ws = (char*)d_ws;
    size_t off = 0;
    auto carve = [&](size_t bytes) -> char* {
        off = (off + 255) & ~(size_t)255;
        char* p = ws + off; off += bytes; return p;
    };
    unsigned* counts   = (unsigned*)carve((size_t)nlocal * 4);
    unsigned* offsets  = (unsigned*)carve(((size_t)nlocal + 1) * 4);
    unsigned* cursor   = (unsigned*)carve((size_t)nlocal * 4);
    unsigned* partials = (unsigned*)carve(256 * 4);
    unsigned* blockoff = (unsigned*)carve(256 * 4);
    float4*   geomA    = (float4*)carve((size_t)nneigh * 16);
    float2*   geomB    = (float2*)carve((size_t)nneigh * 8);

    int nblkS = (nlocal + 1023) / 1024;
    hipMemsetAsync(counts, 0, (size_t)nlocal * 4, stream);
    hist_kernel<<<nblkN, tb, 0, stream>>>(idx0, counts, nneigh);
    scan_partial<<<nblkS, 256, 0, stream>>>(counts, partials, nlocal);
    scan_blockoffs<<<1, 64, 0, stream>>>(partials, blockoff, offsets, nblkS, nlocal);
    scan_final<<<nblkS, 256, 0, stream>>>(counts, blockoff, offsets, cursor, nlocal);
    geom_scatter<<<nblkN, tb, 0, stream>>>(cart, idx0, idx1, neigh_species,
                                           cursor, geomA, geomB, nneigh);
    density_fast<<<(nlocal + 3) / 4, 256, 0, stream>>>(rs, inta, params, offsets,
                                                       geomA, geomB, (float*)d_out, nlocal);
}

// Round 4
// 141.179 us; speedup vs baseline: 2.2318x; 2.2318x over previous
//
#include <hip/hip_runtime.h>
#include <hip/hip_bf16.h>

#define NWAVE 16

constexpr float PI_OVER_CUT = 3.14159265358979323846f / 5.0f;

// ============ fused histogram + coalesced geometry record ============
// record[j] = {dx, dy, dz, dist with species in low 2 mantissa bits}

__global__ __launch_bounds__(256) void prep_hist_geom(
    const float* __restrict__ cart, const int* __restrict__ idx0,
    const int* __restrict__ idx1, const int* __restrict__ nspec,
    unsigned* __restrict__ counts, float4* __restrict__ record, int nneigh)
{
    int j = blockIdx.x * blockDim.x + threadIdx.x;
    if (j >= nneigh) return;
    int i0 = idx0[j], i1 = idx1[j], s = nspec[j];
    float ax = cart[3*i0], ay = cart[3*i0+1], az = cart[3*i0+2];
    float bx = cart[3*i1], by = cart[3*i1+1], bz = cart[3*i1+2];
    float dxv = ax - bx, dyv = ay - by, dzv = az - bz;
    float d2 = dxv*dxv + dyv*dyv + dzv*dzv;
    float rinv = rsqrtf(d2);
    float dist = d2 * rinv;
    unsigned db = (__float_as_uint(dist) & ~3u) | (unsigned)s;
    record[j] = make_float4(dxv * rinv, dyv * rinv, dzv * rinv, __uint_as_float(db));
    atomicAdd(&counts[i0], 1u);
}

// ============ 3-stage parallel exclusive scan (proven in R2) ============

__global__ __launch_bounds__(256) void scan_partial(const unsigned* __restrict__ counts,
                                                    unsigned* __restrict__ partials, int n) {
    __shared__ unsigned wsum[4];
    int t = threadIdx.x;
    int base = blockIdx.x * 1024 + t * 4;
    unsigned s = 0;
    #pragma unroll
    for (int e = 0; e < 4; ++e) { int id = base + e; if (id < n) s += counts[id]; }
    #pragma unroll
    for (int off = 32; off >= 1; off >>= 1) s += __shfl_xor(s, off, 64);
    int lane = t & 63, w = t >> 6;
    if (lane == 0) wsum[w] = s;
    __syncthreads();
    if (t == 0) partials[blockIdx.x] = wsum[0] + wsum[1] + wsum[2] + wsum[3];
}

__global__ __launch_bounds__(64) void scan_blockoffs(const unsigned* __restrict__ partials,
                                                     unsigned* __restrict__ blockoff,
                                                     unsigned* __restrict__ offsets,
                                                     int nblk, int nlocal) {
    int t = threadIdx.x;
    unsigned v = (t < nblk) ? partials[t] : 0u;
    unsigned incl = v;
    #pragma unroll
    for (int off = 1; off < 64; off <<= 1) {
        unsigned u = __shfl_up(incl, off, 64);
        if (t >= off) incl += u;
    }
    if (t < nblk) blockoff[t] = incl - v;
    if (t == nblk - 1) offsets[nlocal] = incl;
}

__global__ __launch_bounds__(256) void scan_final(const unsigned* __restrict__ counts,
                                                  const unsigned* __restrict__ blockoff,
                                                  unsigned* __restrict__ offsets,
                                                  unsigned* __restrict__ cursor, int n) {
    __shared__ unsigned wsum[4];
    int t = threadIdx.x;
    int lane = t & 63, w = t >> 6;
    int base = blockIdx.x * 1024 + t * 4;
    unsigned c[4];
    #pragma unroll
    for (int e = 0; e < 4; ++e) { int id = base + e; c[e] = (id < n) ? counts[id] : 0u; }
    unsigned tsum = c[0] + c[1] + c[2] + c[3];
    unsigned incl = tsum;
    #pragma unroll
    for (int off = 1; off < 64; off <<= 1) {
        unsigned u = __shfl_up(incl, off, 64);
        if (lane >= off) incl += u;
    }
    if (lane == 63) wsum[w] = incl;
    __syncthreads();
    unsigned wpre = 0;
    for (int i = 0; i < 4; ++i) if (i < w) wpre += wsum[i];
    unsigned x = blockoff[blockIdx.x] + wpre + (incl - tsum);
    #pragma unroll
    for (int e = 0; e < 4; ++e) {
        int id = base + e;
        if (id < n) { offsets[id] = x; cursor[id] = x; }
        x += c[e];
    }
}

// ============ permutation scatter (4 B writes only) ============

__global__ __launch_bounds__(256) void scatter_idx(const int* __restrict__ idx0,
                                                   unsigned* __restrict__ cursor,
                                                   unsigned* __restrict__ sorted, int nneigh) {
    int j = blockIdx.x * blockDim.x + threadIdx.x;
    if (j < nneigh) {
        unsigned p = atomicAdd(&cursor[idx0[j]], 1u);
        sorted[p] = (unsigned)j;
    }
}

// ============ density: one wave per atom, 4 neighbors per iteration ============
// lane = g*16 + k: group g handles neighbor n+g, lane channel k.
// Each lane accumulates 10 unique sums {w, wx,wy,wz, xx,yy,zz,xy,xz,yz};
// cross-group reduce via shfl_xor(16|32); l2 uses symmetry (xy==yx etc).

__global__ __launch_bounds__(256) void density_g4(
    const float* __restrict__ rs, const float* __restrict__ inta,
    const float* __restrict__ params, const unsigned* __restrict__ offsets,
    const unsigned* __restrict__ sorted, const float4* __restrict__ record,
    float* __restrict__ out, int nlocal, int nneigh)
{
    int t = threadIdx.x;
    int lane = t & 63;
    int k = lane & 15, g = lane >> 4;
    int a = blockIdx.x * 4 + (t >> 6);
    if (a >= nlocal) return;

    // radial constants, register-resident (4 species x {rs,inta,params})
    float rs0 = rs[k],        rs1 = rs[16 + k],     rs2 = rs[32 + k],     rs3 = rs[48 + k];
    float ia0 = inta[k],      ia1 = inta[16 + k],   ia2 = inta[32 + k],   ia3 = inta[48 + k];
    float pp0 = params[k],    pp1 = params[16 + k], pp2 = params[32 + k], pp3 = params[48 + k];

    int beg = (int)offsets[a], end = (int)offsets[a + 1];
    int lim = nneigh - 1;

    float aw = 0.f, axl = 0.f, ayl = 0.f, azl = 0.f;
    float axx = 0.f, ayy = 0.f, azz = 0.f, axy = 0.f, axz = 0.f, ayz = 0.f;

    // software pipeline: sorted at distance 2, record at distance 1
    int j1;
    float4 rec0;
    {
        int p0 = beg + g;     if (p0 > lim) p0 = lim;
        int jj0 = (int)sorted[p0];
        rec0 = record[jj0];
        int p1 = beg + 4 + g; if (p1 > lim) p1 = lim;
        j1 = (int)sorted[p1];
    }

    for (int n = beg; n < end; n += 4) {
        float4 rec1 = record[j1];                     // for iter n+4
        int p2 = n + 8 + g; if (p2 > lim) p2 = lim;
        int j2 = (int)sorted[p2];                     // for iter n+8

        unsigned u = __float_as_uint(rec0.w);
        float dist = __uint_as_float(u & ~3u);
        bool c1 = (u & 1u) != 0u, c2 = (u & 2u) != 0u;
        float rsel = c2 ? (c1 ? rs3 : rs2) : (c1 ? rs1 : rs0);
        float isel = c2 ? (c1 ? ia3 : ia2) : (c1 ? ia1 : ia0);
        float psel = c2 ? (c1 ? pp3 : pp2) : (c1 ? pp1 : pp0);
        float dd  = dist - rsel;
        float rad = __expf(-isel * dd * dd);
        float fc  = fmaf(0.5f, __cosf(dist * PI_OVER_CUT), 0.5f);
        float w   = rad * fc * fc * psel;
        w = (n + g < end) ? w : 0.f;                  // mask tail lanes

        float dx = rec0.x, dy = rec0.y, dz = rec0.z;
        float wx = w * dx, wy = w * dy, wz = w * dz;
        aw  += w;
        axl += wx;  ayl += wy;  azl += wz;
        axx = fmaf(wx, dx, axx);  axy = fmaf(wx, dy, axy);  axz = fmaf(wx, dz, axz);
        ayy = fmaf(wy, dy, ayy);  ayz = fmaf(wy, dz, ayz);  azz = fmaf(wz, dz, azz);

        rec0 = rec1; j1 = j2;
    }

    #define RED2(x) x += __shfl_xor(x, 16, 64); x += __shfl_xor(x, 32, 64)
    RED2(aw); RED2(axl); RED2(ayl); RED2(azl);
    RED2(axx); RED2(ayy); RED2(azz); RED2(axy); RED2(axz); RED2(ayz);
    #undef RED2

    if (g == 0) {
        float l0 = aw * aw;
        float l1 = axl*axl + ayl*ayl + azl*azl;
        float l2 = axx*axx + ayy*ayy + azz*azz + 2.f*(axy*axy + axz*axz + ayz*ayz);
        out[a*48 + k]      = l0;
        out[a*48 + 16 + k] = l1;
        out[a*48 + 32 + k] = l2;
    }
}

// ============ fallback (R1 path, minimal workspace) ============

__global__ void hist_kernel(const int* __restrict__ idx0, unsigned* __restrict__ counts, int nneigh) {
    int j = blockIdx.x * blockDim.x + threadIdx.x;
    if (j < nneigh) atomicAdd(&counts[idx0[j]], 1u);
}

__global__ void scan_kernel_1blk(const unsigned* __restrict__ counts, unsigned* __restrict__ offsets,
                                 unsigned* __restrict__ cursor, int nlocal) {
    __shared__ unsigned part[1024];
    int t = threadIdx.x;
    int ch = (nlocal + 1023) / 1024;
    int base = t * ch;
    unsigned s = 0;
    for (int i = 0; i < ch; ++i) { int id = base + i; if (id < nlocal) s += counts[id]; }
    part[t] = s;
    __syncthreads();
    for (int off = 1; off < 1024; off <<= 1) {
        unsigned v = (t >= off) ? part[t - off] : 0u;
        __syncthreads();
        part[t] += v;
        __syncthreads();
    }
    unsigned run = (t == 0) ? 0u : part[t - 1];
    for (int i = 0; i < ch; ++i) {
        int id = base + i;
        if (id < nlocal) { offsets[id] = run; cursor[id] = run; run += counts[id]; }
    }
    if (t == 1023) offsets[nlocal] = part[1023];
}

__global__ __launch_bounds__(256) void density_kernel(
    const float* __restrict__ cart, const float* __restrict__ rs,
    const float* __restrict__ inta, const float* __restrict__ params,
    const int* __restrict__ idx1, const int* __restrict__ nspec,
    const unsigned* __restrict__ offsets, const unsigned* __restrict__ sorted,
    float* __restrict__ out, int nlocal)
{
    int lane = threadIdx.x & 63;
    int a = blockIdx.x * 4 + (threadIdx.x >> 6);
    if (a >= nlocal) return;
    int k = lane & 15;
    int g = lane >> 4;
    float c0x = cart[3*a], c0y = cart[3*a+1], c0z = cart[3*a+2];
    int a1, b1, a2, b2;
    switch (g) {
      case 0:  a1=0; b1=0; a2=1; b2=1; break;
      case 1:  a1=0; b1=1; a2=1; b2=2; break;
      case 2:  a1=0; b1=2; a2=2; b2=0; break;
      default: a1=1; b1=0; a2=2; b2=1; break;
    }
    float acc0 = 0.f, acc1 = 0.f, acc2 = 0.f, acc3 = 0.f;
    unsigned beg = offsets[a], end = offsets[a + 1];
    for (unsigned n = beg; n < end; ++n) {
        int j  = (int)sorted[n];
        int i1 = idx1[j];
        int s  = nspec[j];
        float dxv = c0x - cart[3*i1];
        float dyv = c0y - cart[3*i1+1];
        float dzv = c0z - cart[3*i1+2];
        float d2   = dxv*dxv + dyv*dyv + dzv*dzv;
        float rinv = rsqrtf(d2);
        float dist = d2 * rinv;
        float dx = dxv * rinv, dy = dyv * rinv, dz = dzv * rinv;
        float fc   = 0.5f * __cosf(dist * PI_OVER_CUT) + 0.5f;
        float fcut = fc * fc;
        float tt   = dist - rs[s*NWAVE + k];
        float rad  = __expf(-inta[s*NWAVE + k] * tt * tt) * params[s*NWAVE + k];
        float f1 = (g == 0) ? fcut : fcut * (g == 1 ? dx : (g == 2 ? dy : dz));
        acc0 = fmaf(f1, rad, acc0);
        float pa1 = (a1 == 0 ? dx : (a1 == 1 ? dy : dz));
        float pb1 = (b1 == 0 ? dx : (b1 == 1 ? dy : dz));
        acc1 = fmaf(fcut * pa1 * pb1, rad, acc1);
        float pa2 = (a2 == 0 ? dx : (a2 == 1 ? dy : dz));
        float pb2 = (b2 == 0 ? dx : (b2 == 1 ? dy : dz));
        acc2 = fmaf(fcut * pa2 * pb2, rad, acc2);
        if (g == 0) acc3 = fmaf(fcut * dz * dz, rad, acc3);
    }
    float l0, l1, l2;
    if (g == 0) { l0 = acc0*acc0; l1 = 0.f;        l2 = acc1*acc1 + acc2*acc2 + acc3*acc3; }
    else        { l0 = 0.f;       l1 = acc0*acc0;  l2 = acc1*acc1 + acc2*acc2; }
    l0 += __shfl_xor(l0, 16, 64); l1 += __shfl_xor(l1, 16, 64); l2 += __shfl_xor(l2, 16, 64);
    l0 += __shfl_xor(l0, 32, 64); l1 += __shfl_xor(l1, 32, 64); l2 += __shfl_xor(l2, 32, 64);
    if (g == 0) {
        out[a*48 + k]      = l0;
        out[a*48 + 16 + k] = l1;
        out[a*48 + 32 + k] = l2;
    }
}

// ======================= launch =======================

extern "C" void kernel_launch(void* const* d_in, const int* in_sizes, int n_in,
                              void* d_out, int out_size, void* d_ws, size_t ws_size,
                              hipStream_t stream) {
    const float* cart   = (const float*)d_in[0];
    const float* rs     = (const float*)d_in[1];
    const float* inta   = (const float*)d_in[2];
    const float* params = (const float*)d_in[3];
    const int* atom_index    = (const int*)d_in[4];
    const int* neigh_species = (const int*)d_in[6];
    int nlocal = in_sizes[5];
    int nneigh = in_sizes[6];
    const int* idx0 = atom_index;
    const int* idx1 = atom_index + nneigh;

    int tb = 256;
    int nblkN = (nneigh + tb - 1) / tb;
    int nblkS = (nlocal + 1023) / 1024;

    char* ws = (char*)d_ws;
    size_t off = 0;
    auto carve = [&](size_t bytes) -> char* {
        off = (off + 255) & ~(size_t)255;
        char* p = ws + off; off += bytes; return p;
    };
    unsigned* counts   = (unsigned*)carve((size_t)nlocal * 4);
    unsigned* offsets  = (unsigned*)carve(((size_t)nlocal + 1) * 4);
    unsigned* cursor   = (unsigned*)carve((size_t)nlocal * 4);
    unsigned* partials = (unsigned*)carve(256 * 4);
    unsigned* blockoff = (unsigned*)carve(256 * 4);
    unsigned* sorted   = (unsigned*)carve((size_t)nneigh * 4);
    float4*   record   = (float4*)carve((size_t)nneigh * 16);
    size_t need_fast = off;

    hipMemsetAsync(counts, 0, (size_t)nlocal * 4, stream);

    if (ws_size >= need_fast && nblkS <= 64) {
        prep_hist_geom<<<nblkN, tb, 0, stream>>>(cart, idx0, idx1, neigh_species,
                                                 counts, record, nneigh);
        scan_partial<<<nblkS, 256, 0, stream>>>(counts, partials, nlocal);
        scan_blockoffs<<<1, 64, 0, stream>>>(partials, blockoff, offsets, nblkS, nlocal);
        scan_final<<<nblkS, 256, 0, stream>>>(counts, blockoff, offsets, cursor, nlocal);
        scatter_idx<<<nblkN, tb, 0, stream>>>(idx0, cursor, sorted, nneigh);
        density_g4<<<(nlocal + 3) / 4, 256, 0, stream>>>(rs, inta, params, offsets, sorted,
                                                         record, (float*)d_out, nlocal, nneigh);
    } else {
        // minimal-workspace fallback (R1 path)
        hist_kernel<<<nblkN, tb, 0, stream>>>(idx0, counts, nneigh);
        scan_kernel_1blk<<<1, 1024, 0, stream>>>(counts, offsets, cursor, nlocal);
        scatter_idx<<<nblkN, tb, 0, stream>>>(idx0, cursor, sorted, nneigh);
        density_kernel<<<(nlocal + 3) / 4, 256, 0, stream>>>(cart, rs, inta, params, idx1,
                                                             neigh_species, offsets, sorted,
                                                             (float*)d_out, nlocal);
    }
}

// Round 5
// 101.545 us; speedup vs baseline: 3.1029x; 1.3903x over previous
//
#include <hip/hip_runtime.h>
#include <hip/hip_bf16.h>

#define NWAVE 16
#define LOG2CHUNK 14
#define CHUNK (1 << LOG2CHUNK)
#define HIST_WORDS 10240   // static LDS: 40KB = 20480 u16 bins (covers nlocal<=40960)

constexpr float PI_OVER_CUT = 3.14159265358979323846f / 5.0f;

// ============ record build: pure streaming, NO atomics ============
// record[j] = {dx, dy, dz, dist with species in low 2 mantissa bits}

__global__ __launch_bounds__(256) void prep_record(
    const float* __restrict__ cart, const int* __restrict__ idx0,
    const int* __restrict__ idx1, const int* __restrict__ nspec,
    float4* __restrict__ record, int nneigh)
{
    int j = blockIdx.x * blockDim.x + threadIdx.x;
    if (j >= nneigh) return;
    int i0 = idx0[j], i1 = idx1[j], s = nspec[j];
    float ax = cart[3*i0], ay = cart[3*i0+1], az = cart[3*i0+2];
    float bx = cart[3*i1], by = cart[3*i1+1], bz = cart[3*i1+2];
    float dxv = ax - bx, dyv = ay - by, dzv = az - bz;
    float d2 = dxv*dxv + dyv*dyv + dzv*dzv;
    float rinv = rsqrtf(d2);
    float dist = d2 * rinv;
    unsigned db = (__float_as_uint(dist) & ~3u) | (unsigned)s;
    record[j] = make_float4(dxv * rinv, dyv * rinv, dzv * rinv, __uint_as_float(db));
}

// ============ per-chunk LDS histogram + local rank (NO global atomics) ============
// WG bid: chunk c = bid>>1, parity p = bid&1. Handles atoms with (a&1)==p.
// bin = a>>1; u16-packed counts in LDS; lrank[j] = rank within (chunk, atom).

__global__ __launch_bounds__(1024) void chunk_hist_rank(
    const int* __restrict__ idx0, unsigned short* __restrict__ lrank,
    unsigned short* __restrict__ hist16, int nneigh, int halfp)
{
    __shared__ unsigned lds[HIST_WORDS];
    int c = blockIdx.x >> 1;
    int parity = blockIdx.x & 1;
    int t = threadIdx.x;

    int words = halfp >> 1;
    for (int w = t; w < words; w += 1024) lds[w] = 0u;
    __syncthreads();

    int jbeg = c << LOG2CHUNK;
    int jend = jbeg + CHUNK; if (jend > nneigh) jend = nneigh;
    for (int j = jbeg + t; j < jend; j += 1024) {
        int a = idx0[j];
        if ((a & 1) == parity) {
            int bin = a >> 1;
            int word = bin >> 1;
            int shift = (bin & 1) << 4;
            unsigned old = atomicAdd(&lds[word], 1u << shift);
            lrank[j] = (unsigned short)((old >> shift) & 0xffffu);
        }
    }
    __syncthreads();

    unsigned* hrow = (unsigned*)(hist16 + (size_t)blockIdx.x * halfp);
    for (int w = t; w < words; w += 1024) hrow[w] = lds[w];
}

// ============ per-atom chunk prefix + totals ============
// counts[a] = sum_c hist[c][a];  chunkpre[a][c] = prefix over chunks.

__global__ __launch_bounds__(256) void combine_pre(
    const unsigned short* __restrict__ hist16, unsigned* __restrict__ counts,
    unsigned short* __restrict__ chunkpre, int nlocal, int nc, int halfp)
{
    int a = blockIdx.x * blockDim.x + threadIdx.x;
    if (a >= nlocal) return;
    int parity = a & 1;
    int bin = a >> 1;
    unsigned run = 0;
    for (int c = 0; c < nc; ++c) {
        unsigned h = hist16[(size_t)(c*2 + parity) * halfp + bin];
        chunkpre[(size_t)a * nc + c] = (unsigned short)run;
        run += h;
    }
    counts[a] = run;
}

// ============ 3-stage parallel exclusive scan (proven) ============

__global__ __launch_bounds__(256) void scan_partial(const unsigned* __restrict__ counts,
                                                    unsigned* __restrict__ partials, int n) {
    __shared__ unsigned wsum[4];
    int t = threadIdx.x;
    int base = blockIdx.x * 1024 + t * 4;
    unsigned s = 0;
    #pragma unroll
    for (int e = 0; e < 4; ++e) { int id = base + e; if (id < n) s += counts[id]; }
    #pragma unroll
    for (int off = 32; off >= 1; off >>= 1) s += __shfl_xor(s, off, 64);
    int lane = t & 63, w = t >> 6;
    if (lane == 0) wsum[w] = s;
    __syncthreads();
    if (t == 0) partials[blockIdx.x] = wsum[0] + wsum[1] + wsum[2] + wsum[3];
}

__global__ __launch_bounds__(64) void scan_blockoffs(const unsigned* __restrict__ partials,
                                                     unsigned* __restrict__ blockoff,
                                                     unsigned* __restrict__ offsets,
                                                     int nblk, int nlocal) {
    int t = threadIdx.x;
    unsigned v = (t < nblk) ? partials[t] : 0u;
    unsigned incl = v;
    #pragma unroll
    for (int off = 1; off < 64; off <<= 1) {
        unsigned u = __shfl_up(incl, off, 64);
        if (t >= off) incl += u;
    }
    if (t < nblk) blockoff[t] = incl - v;
    if (t == nblk - 1) offsets[nlocal] = incl;
}

__global__ __launch_bounds__(256) void scan_final(const unsigned* __restrict__ counts,
                                                  const unsigned* __restrict__ blockoff,
                                                  unsigned* __restrict__ offsets, int n) {
    __shared__ unsigned wsum[4];
    int t = threadIdx.x;
    int lane = t & 63, w = t >> 6;
    int base = blockIdx.x * 1024 + t * 4;
    unsigned c[4];
    #pragma unroll
    for (int e = 0; e < 4; ++e) { int id = base + e; c[e] = (id < n) ? counts[id] : 0u; }
    unsigned tsum = c[0] + c[1] + c[2] + c[3];
    unsigned incl = tsum;
    #pragma unroll
    for (int off = 1; off < 64; off <<= 1) {
        unsigned u = __shfl_up(incl, off, 64);
        if (lane >= off) incl += u;
    }
    if (lane == 63) wsum[w] = incl;
    __syncthreads();
    unsigned wpre = 0;
    for (int i = 0; i < 4; ++i) if (i < w) wpre += wsum[i];
    unsigned x = blockoff[blockIdx.x] + wpre + (incl - tsum);
    #pragma unroll
    for (int e = 0; e < 4; ++e) {
        int id = base + e;
        if (id < n) offsets[id] = x;
        x += c[e];
    }
}

// ============ atomic-free permutation scatter ============

__global__ __launch_bounds__(256) void scatter_direct(
    const int* __restrict__ idx0, const unsigned short* __restrict__ lrank,
    const unsigned* __restrict__ offsets, const unsigned short* __restrict__ chunkpre,
    unsigned* __restrict__ sorted, int nneigh, int nc)
{
    int j = blockIdx.x * blockDim.x + threadIdx.x;
    if (j >= nneigh) return;
    int c = j >> LOG2CHUNK;
    int a = idx0[j];
    unsigned p = offsets[a] + (unsigned)chunkpre[(size_t)a * nc + c] + (unsigned)lrank[j];
    sorted[p] = (unsigned)j;
}

// ============ density: one wave per atom, 4 neighbors per iteration ============

__global__ __launch_bounds__(256) void density_g4(
    const float* __restrict__ rs, const float* __restrict__ inta,
    const float* __restrict__ params, const unsigned* __restrict__ offsets,
    const unsigned* __restrict__ sorted, const float4* __restrict__ record,
    float* __restrict__ out, int nlocal, int nneigh)
{
    int t = threadIdx.x;
    int lane = t & 63;
    int k = lane & 15, g = lane >> 4;
    int a = blockIdx.x * 4 + (t >> 6);
    if (a >= nlocal) return;

    float rs0 = rs[k],        rs1 = rs[16 + k],     rs2 = rs[32 + k],     rs3 = rs[48 + k];
    float ia0 = inta[k],      ia1 = inta[16 + k],   ia2 = inta[32 + k],   ia3 = inta[48 + k];
    float pp0 = params[k],    pp1 = params[16 + k], pp2 = params[32 + k], pp3 = params[48 + k];

    int beg = (int)offsets[a], end = (int)offsets[a + 1];
    int lim = nneigh - 1;

    float aw = 0.f, axl = 0.f, ayl = 0.f, azl = 0.f;
    float axx = 0.f, ayy = 0.f, azz = 0.f, axy = 0.f, axz = 0.f, ayz = 0.f;

    int j1;
    float4 rec0;
    {
        int p0 = beg + g;     if (p0 > lim) p0 = lim;
        int jj0 = (int)sorted[p0];
        rec0 = record[jj0];
        int p1 = beg + 4 + g; if (p1 > lim) p1 = lim;
        j1 = (int)sorted[p1];
    }

    for (int n = beg; n < end; n += 4) {
        float4 rec1 = record[j1];
        int p2 = n + 8 + g; if (p2 > lim) p2 = lim;
        int j2 = (int)sorted[p2];

        unsigned u = __float_as_uint(rec0.w);
        float dist = __uint_as_float(u & ~3u);
        bool c1 = (u & 1u) != 0u, c2 = (u & 2u) != 0u;
        float rsel = c2 ? (c1 ? rs3 : rs2) : (c1 ? rs1 : rs0);
        float isel = c2 ? (c1 ? ia3 : ia2) : (c1 ? ia1 : ia0);
        float psel = c2 ? (c1 ? pp3 : pp2) : (c1 ? pp1 : pp0);
        float dd  = dist - rsel;
        float rad = __expf(-isel * dd * dd);
        float fc  = fmaf(0.5f, __cosf(dist * PI_OVER_CUT), 0.5f);
        float w   = rad * fc * fc * psel;
        w = (n + g < end) ? w : 0.f;

        float dx = rec0.x, dy = rec0.y, dz = rec0.z;
        float wx = w * dx, wy = w * dy, wz = w * dz;
        aw  += w;
        axl += wx;  ayl += wy;  azl += wz;
        axx = fmaf(wx, dx, axx);  axy = fmaf(wx, dy, axy);  axz = fmaf(wx, dz, axz);
        ayy = fmaf(wy, dy, ayy);  ayz = fmaf(wy, dz, ayz);  azz = fmaf(wz, dz, azz);

        rec0 = rec1; j1 = j2;
    }

    #define RED2(x) x += __shfl_xor(x, 16, 64); x += __shfl_xor(x, 32, 64)
    RED2(aw); RED2(axl); RED2(ayl); RED2(azl);
    RED2(axx); RED2(ayy); RED2(azz); RED2(axy); RED2(axz); RED2(ayz);
    #undef RED2

    if (g == 0) {
        float l0 = aw * aw;
        float l1 = axl*axl + ayl*ayl + azl*azl;
        float l2 = axx*axx + ayy*ayy + azz*azz + 2.f*(axy*axy + axz*axz + ayz*ayz);
        out[a*48 + k]      = l0;
        out[a*48 + 16 + k] = l1;
        out[a*48 + 32 + k] = l2;
    }
}

// ============ fallback (R1/R4-proven path, minimal workspace) ============

__global__ void hist_kernel(const int* __restrict__ idx0, unsigned* __restrict__ counts, int nneigh) {
    int j = blockIdx.x * blockDim.x + threadIdx.x;
    if (j < nneigh) atomicAdd(&counts[idx0[j]], 1u);
}

__global__ void scan_kernel_1blk(const unsigned* __restrict__ counts, unsigned* __restrict__ offsets,
                                 unsigned* __restrict__ cursor, int nlocal) {
    __shared__ unsigned part[1024];
    int t = threadIdx.x;
    int ch = (nlocal + 1023) / 1024;
    int base = t * ch;
    unsigned s = 0;
    for (int i = 0; i < ch; ++i) { int id = base + i; if (id < nlocal) s += counts[id]; }
    part[t] = s;
    __syncthreads();
    for (int off = 1; off < 1024; off <<= 1) {
        unsigned v = (t >= off) ? part[t - off] : 0u;
        __syncthreads();
        part[t] += v;
        __syncthreads();
    }
    unsigned run = (t == 0) ? 0u : part[t - 1];
    for (int i = 0; i < ch; ++i) {
        int id = base + i;
        if (id < nlocal) { offsets[id] = run; cursor[id] = run; run += counts[id]; }
    }
    if (t == 1023) offsets[nlocal] = part[1023];
}

__global__ __launch_bounds__(256) void scatter_idx(const int* __restrict__ idx0,
                                                   unsigned* __restrict__ cursor,
                                                   unsigned* __restrict__ sorted, int nneigh) {
    int j = blockIdx.x * blockDim.x + threadIdx.x;
    if (j < nneigh) {
        unsigned p = atomicAdd(&cursor[idx0[j]], 1u);
        sorted[p] = (unsigned)j;
    }
}

__global__ __launch_bounds__(256) void density_kernel(
    const float* __restrict__ cart, const float* __restrict__ rs,
    const float* __restrict__ inta, const float* __restrict__ params,
    const int* __restrict__ idx1, const int* __restrict__ nspec,
    const unsigned* __restrict__ offsets, const unsigned* __restrict__ sorted,
    float* __restrict__ out, int nlocal)
{
    int lane = threadIdx.x & 63;
    int a = blockIdx.x * 4 + (threadIdx.x >> 6);
    if (a >= nlocal) return;
    int k = lane & 15;
    int g = lane >> 4;
    float c0x = cart[3*a], c0y = cart[3*a+1], c0z = cart[3*a+2];
    int a1, b1, a2, b2;
    switch (g) {
      case 0:  a1=0; b1=0; a2=1; b2=1; break;
      case 1:  a1=0; b1=1; a2=1; b2=2; break;
      case 2:  a1=0; b1=2; a2=2; b2=0; break;
      default: a1=1; b1=0; a2=2; b2=1; break;
    }
    float acc0 = 0.f, acc1 = 0.f, acc2 = 0.f, acc3 = 0.f;
    unsigned beg = offsets[a], end = offsets[a + 1];
    for (unsigned n = beg; n < end; ++n) {
        int j  = (int)sorted[n];
        int i1 = idx1[j];
        int s  = nspec[j];
        float dxv = c0x - cart[3*i1];
        float dyv = c0y - cart[3*i1+1];
        float dzv = c0z - cart[3*i1+2];
        float d2   = dxv*dxv + dyv*dyv + dzv*dzv;
        float rinv = rsqrtf(d2);
        float dist = d2 * rinv;
        float dx = dxv * rinv, dy = dyv * rinv, dz = dzv * rinv;
        float fc   = 0.5f * __cosf(dist * PI_OVER_CUT) + 0.5f;
        float fcut = fc * fc;
        float tt   = dist - rs[s*NWAVE + k];
        float rad  = __expf(-inta[s*NWAVE + k] * tt * tt) * params[s*NWAVE + k];
        float f1 = (g == 0) ? fcut : fcut * (g == 1 ? dx : (g == 2 ? dy : dz));
        acc0 = fmaf(f1, rad, acc0);
        float pa1 = (a1 == 0 ? dx : (a1 == 1 ? dy : dz));
        float pb1 = (b1 == 0 ? dx : (b1 == 1 ? dy : dz));
        acc1 = fmaf(fcut * pa1 * pb1, rad, acc1);
        float pa2 = (a2 == 0 ? dx : (a2 == 1 ? dy : dz));
        float pb2 = (b2 == 0 ? dx : (b2 == 1 ? dy : dz));
        acc2 = fmaf(fcut * pa2 * pb2, rad, acc2);
        if (g == 0) acc3 = fmaf(fcut * dz * dz, rad, acc3);
    }
    float l0, l1, l2;
    if (g == 0) { l0 = acc0*acc0; l1 = 0.f;        l2 = acc1*acc1 + acc2*acc2 + acc3*acc3; }
    else        { l0 = 0.f;       l1 = acc0*acc0;  l2 = acc1*acc1 + acc2*acc2; }
    l0 += __shfl_xor(l0, 16, 64); l1 += __shfl_xor(l1, 16, 64); l2 += __shfl_xor(l2, 16, 64);
    l0 += __shfl_xor(l0, 32, 64); l1 += __shfl_xor(l1, 32, 64); l2 += __shfl_xor(l2, 32, 64);
    if (g == 0) {
        out[a*48 + k]      = l0;
        out[a*48 + 16 + k] = l1;
        out[a*48 + 32 + k] = l2;
    }
}

// ======================= launch =======================

extern "C" void kernel_launch(void* const* d_in, const int* in_sizes, int n_in,
                              void* d_out, int out_size, void* d_ws, size_t ws_size,
                              hipStream_t stream) {
    const float* cart   = (const float*)d_in[0];
    const float* rs     = (const float*)d_in[1];
    const float* inta   = (const float*)d_in[2];
    const float* params = (const float*)d_in[3];
    const int* atom_index    = (const int*)d_in[4];
    const int* neigh_species = (const int*)d_in[6];
    int nlocal = in_sizes[5];
    int nneigh = in_sizes[6];
    const int* idx0 = atom_index;
    const int* idx1 = atom_index + nneigh;

    int tb = 256;
    int nblkN = (nneigh + tb - 1) / tb;
    int nblkS = (nlocal + 1023) / 1024;
    int nc = (nneigh + CHUNK - 1) >> LOG2CHUNK;
    int halfp = (((nlocal + 1) >> 1) + 63) & ~63;   // padded bins per parity

    char* ws = (char*)d_ws;
    size_t off = 0;
    auto carve = [&](size_t bytes) -> char* {
        off = (off + 255) & ~(size_t)255;
        char* p = ws + off; off += bytes; return p;
    };
    unsigned* counts        = (unsigned*)carve((size_t)nlocal * 4);
    unsigned* offsets       = (unsigned*)carve(((size_t)nlocal + 1) * 4);
    unsigned* cursor        = (unsigned*)carve((size_t)nlocal * 4);
    unsigned* partials      = (unsigned*)carve(256 * 4);
    unsigned* blockoff      = (unsigned*)carve(256 * 4);
    unsigned* sorted        = (unsigned*)carve((size_t)nneigh * 4);
    float4*   record        = (float4*)carve((size_t)nneigh * 16);
    unsigned short* lrank   = (unsigned short*)carve((size_t)nneigh * 2);
    unsigned short* hist16  = (unsigned short*)carve((size_t)nc * 2 * halfp * 2);
    unsigned short* chunkpre= (unsigned short*)carve((size_t)nlocal * nc * 2);
    size_t need_fast = off;

    bool fast = (ws_size >= need_fast) && (nblkS <= 64) && (halfp <= 2 * HIST_WORDS) && (nc <= 64);

    if (fast) {
        prep_record<<<nblkN, tb, 0, stream>>>(cart, idx0, idx1, neigh_species, record, nneigh);
        chunk_hist_rank<<<nc * 2, 1024, 0, stream>>>(idx0, lrank, hist16, nneigh, halfp);
        combine_pre<<<(nlocal + tb - 1) / tb, tb, 0, stream>>>(hist16, counts, chunkpre,
                                                               nlocal, nc, halfp);
        scan_partial<<<nblkS, 256, 0, stream>>>(counts, partials, nlocal);
        scan_blockoffs<<<1, 64, 0, stream>>>(partials, blockoff, offsets, nblkS, nlocal);
        scan_final<<<nblkS, 256, 0, stream>>>(counts, blockoff, offsets, nlocal);
        scatter_direct<<<nblkN, tb, 0, stream>>>(idx0, lrank, offsets, chunkpre,
                                                 sorted, nneigh, nc);
        density_g4<<<(nlocal + 3) / 4, 256, 0, stream>>>(rs, inta, params, offsets, sorted,
                                                         record, (float*)d_out, nlocal, nneigh);
    } else {
        hipMemsetAsync(counts, 0, (size_t)nlocal * 4, stream);
        hist_kernel<<<nblkN, tb, 0, stream>>>(idx0, counts, nneigh);
        scan_kernel_1blk<<<1, 1024, 0, stream>>>(counts, offsets, cursor, nlocal);
        scatter_idx<<<nblkN, tb, 0, stream>>>(idx0, cursor, sorted, nneigh);
        density_kernel<<<(nlocal + 3) / 4, 256, 0, stream>>>(cart, rs, inta, params, idx1,
                                                             neigh_species, offsets, sorted,
                                                             (float*)d_out, nlocal);
    }
}

// Round 6
// 85.131 us; speedup vs baseline: 3.7012x; 1.1928x over previous
//
#include <hip/hip_runtime.h>
#include <hip/hip_bf16.h>

#define NWAVE 16
#define LOG2CHUNK 14
#define CHUNK (1 << LOG2CHUNK)
#define HIST_WORDS 10240   // static LDS: 40KB = 20480 u16 bins (covers nlocal<=40960)

constexpr float PI_OVER_CUT = 3.14159265358979323846f / 5.0f;

// ============ per-chunk LDS histogram + local rank (NO global atomics) ============
// WG bid: chunk c = bid>>1, parity = bid&1. Handles atoms with (a&1)==parity.
// bin = a>>1; u16-packed counts in LDS; lrank[j] = rank within (chunk, atom).

__global__ __launch_bounds__(1024) void chunk_hist_rank(
    const int* __restrict__ idx0, unsigned short* __restrict__ lrank,
    unsigned short* __restrict__ hist16, int nneigh, int halfp)
{
    __shared__ unsigned lds[HIST_WORDS];
    int c = blockIdx.x >> 1;
    int parity = blockIdx.x & 1;
    int t = threadIdx.x;

    int words = halfp >> 1;
    for (int w = t; w < words; w += 1024) lds[w] = 0u;
    __syncthreads();

    int jbeg = c << LOG2CHUNK;
    int jend = jbeg + CHUNK; if (jend > nneigh) jend = nneigh;
    for (int j = jbeg + t; j < jend; j += 1024) {
        int a = idx0[j];
        if ((a & 1) == parity) {
            int bin = a >> 1;
            int word = bin >> 1;
            int shift = (bin & 1) << 4;
            unsigned old = atomicAdd(&lds[word], 1u << shift);
            lrank[j] = (unsigned short)((old >> shift) & 0xffffu);
        }
    }
    __syncthreads();

    unsigned* hrow = (unsigned*)(hist16 + (size_t)blockIdx.x * halfp);
    for (int w = t; w < words; w += 1024) hrow[w] = lds[w];
}

// ============ per-atom chunk prefix + totals ============

__global__ __launch_bounds__(256) void combine_pre(
    const unsigned short* __restrict__ hist16, unsigned* __restrict__ counts,
    unsigned short* __restrict__ chunkpre, int nlocal, int nc, int halfp)
{
    int a = blockIdx.x * blockDim.x + threadIdx.x;
    if (a >= nlocal) return;
    int parity = a & 1;
    int bin = a >> 1;
    unsigned run = 0;
    for (int c = 0; c < nc; ++c) {
        unsigned h = hist16[(size_t)(c*2 + parity) * halfp + bin];
        chunkpre[(size_t)a * nc + c] = (unsigned short)run;
        run += h;
    }
    counts[a] = run;
}

// ============ 3-stage parallel exclusive scan (proven) ============

__global__ __launch_bounds__(256) void scan_partial(const unsigned* __restrict__ counts,
                                                    unsigned* __restrict__ partials, int n) {
    __shared__ unsigned wsum[4];
    int t = threadIdx.x;
    int base = blockIdx.x * 1024 + t * 4;
    unsigned s = 0;
    #pragma unroll
    for (int e = 0; e < 4; ++e) { int id = base + e; if (id < n) s += counts[id]; }
    #pragma unroll
    for (int off = 32; off >= 1; off >>= 1) s += __shfl_xor(s, off, 64);
    int lane = t & 63, w = t >> 6;
    if (lane == 0) wsum[w] = s;
    __syncthreads();
    if (t == 0) partials[blockIdx.x] = wsum[0] + wsum[1] + wsum[2] + wsum[3];
}

__global__ __launch_bounds__(64) void scan_blockoffs(const unsigned* __restrict__ partials,
                                                     unsigned* __restrict__ blockoff,
                                                     unsigned* __restrict__ offsets,
                                                     int nblk, int nlocal) {
    int t = threadIdx.x;
    unsigned v = (t < nblk) ? partials[t] : 0u;
    unsigned incl = v;
    #pragma unroll
    for (int off = 1; off < 64; off <<= 1) {
        unsigned u = __shfl_up(incl, off, 64);
        if (t >= off) incl += u;
    }
    if (t < nblk) blockoff[t] = incl - v;
    if (t == nblk - 1) offsets[nlocal] = incl;
}

__global__ __launch_bounds__(256) void scan_final(const unsigned* __restrict__ counts,
                                                  const unsigned* __restrict__ blockoff,
                                                  unsigned* __restrict__ offsets, int n) {
    __shared__ unsigned wsum[4];
    int t = threadIdx.x;
    int lane = t & 63, w = t >> 6;
    int base = blockIdx.x * 1024 + t * 4;
    unsigned c[4];
    #pragma unroll
    for (int e = 0; e < 4; ++e) { int id = base + e; c[e] = (id < n) ? counts[id] : 0u; }
    unsigned tsum = c[0] + c[1] + c[2] + c[3];
    unsigned incl = tsum;
    #pragma unroll
    for (int off = 1; off < 64; off <<= 1) {
        unsigned u = __shfl_up(incl, off, 64);
        if (lane >= off) incl += u;
    }
    if (lane == 63) wsum[w] = incl;
    __syncthreads();
    unsigned wpre = 0;
    for (int i = 0; i < 4; ++i) if (i < w) wpre += wsum[i];
    unsigned x = blockoff[blockIdx.x] + wpre + (incl - tsum);
    #pragma unroll
    for (int e = 0; e < 4; ++e) {
        int id = base + e;
        if (id < n) offsets[id] = x;
        x += c[e];
    }
}

// ============ fused geometry + atomic-free record scatter ============
// srec[p] = {dx, dy, dz, dist with species in low 2 mantissa bits}, p = sorted pos.

__global__ __launch_bounds__(256) void geom_scatter_direct(
    const float* __restrict__ cart, const int* __restrict__ idx0,
    const int* __restrict__ idx1, const int* __restrict__ nspec,
    const unsigned short* __restrict__ lrank, const unsigned* __restrict__ offsets,
    const unsigned short* __restrict__ chunkpre, float4* __restrict__ srec,
    int nneigh, int nc)
{
    int j = blockIdx.x * blockDim.x + threadIdx.x;
    if (j >= nneigh) return;
    int i0 = idx0[j], i1 = idx1[j], s = nspec[j];
    int c = j >> LOG2CHUNK;
    unsigned p = offsets[i0] + (unsigned)chunkpre[(size_t)i0 * nc + c] + (unsigned)lrank[j];
    float ax = cart[3*i0], ay = cart[3*i0+1], az = cart[3*i0+2];
    float bx = cart[3*i1], by = cart[3*i1+1], bz = cart[3*i1+2];
    float dxv = ax - bx, dyv = ay - by, dzv = az - bz;
    float d2 = dxv*dxv + dyv*dyv + dzv*dzv;
    float rinv = rsqrtf(d2);
    float dist = d2 * rinv;
    unsigned db = (__float_as_uint(dist) & ~3u) | (unsigned)s;
    srec[p] = make_float4(dxv * rinv, dyv * rinv, dzv * rinv, __uint_as_float(db));
}

// ============ density: one wave per atom, pure streaming reads ============
// lane = g*16+k: group g handles record beg+n+g, channel k. 10 unique sums.

__global__ __launch_bounds__(256) void density_seq(
    const float* __restrict__ rs, const float* __restrict__ inta,
    const float* __restrict__ params, const unsigned* __restrict__ offsets,
    const float4* __restrict__ srec, float* __restrict__ out,
    int nlocal, int nneigh)
{
    int t = threadIdx.x;
    int lane = t & 63;
    int k = lane & 15, g = lane >> 4;
    int a = blockIdx.x * 4 + (t >> 6);
    if (a >= nlocal) return;

    float rs0 = rs[k],        rs1 = rs[16 + k],     rs2 = rs[32 + k],     rs3 = rs[48 + k];
    float ia0 = inta[k],      ia1 = inta[16 + k],   ia2 = inta[32 + k],   ia3 = inta[48 + k];
    float pp0 = params[k],    pp1 = params[16 + k], pp2 = params[32 + k], pp3 = params[48 + k];

    int beg = (int)offsets[a], end = (int)offsets[a + 1];
    int lim = nneigh - 1;

    float aw = 0.f, axl = 0.f, ayl = 0.f, azl = 0.f;
    float axx = 0.f, ayy = 0.f, azz = 0.f, axy = 0.f, axz = 0.f, ayz = 0.f;

    // simple 1-deep pipeline on the streaming read
    int p0 = beg + g; if (p0 > lim) p0 = lim;
    float4 rec0 = srec[p0];

    for (int n = beg; n < end; n += 4) {
        int p1 = n + 4 + g; if (p1 > lim) p1 = lim;
        float4 rec1 = srec[p1];

        unsigned u = __float_as_uint(rec0.w);
        float dist = __uint_as_float(u & ~3u);
        bool c1 = (u & 1u) != 0u, c2 = (u & 2u) != 0u;
        float rsel = c2 ? (c1 ? rs3 : rs2) : (c1 ? rs1 : rs0);
        float isel = c2 ? (c1 ? ia3 : ia2) : (c1 ? ia1 : ia0);
        float psel = c2 ? (c1 ? pp3 : pp2) : (c1 ? pp1 : pp0);
        float dd  = dist - rsel;
        float rad = __expf(-isel * dd * dd);
        float fc  = fmaf(0.5f, __cosf(dist * PI_OVER_CUT), 0.5f);
        float w   = rad * fc * fc * psel;
        w = (n + g < end) ? w : 0.f;

        float dx = rec0.x, dy = rec0.y, dz = rec0.z;
        float wx = w * dx, wy = w * dy, wz = w * dz;
        aw  += w;
        axl += wx;  ayl += wy;  azl += wz;
        axx = fmaf(wx, dx, axx);  axy = fmaf(wx, dy, axy);  axz = fmaf(wx, dz, axz);
        ayy = fmaf(wy, dy, ayy);  ayz = fmaf(wy, dz, ayz);  azz = fmaf(wz, dz, azz);

        rec0 = rec1;
    }

    #define RED2(x) x += __shfl_xor(x, 16, 64); x += __shfl_xor(x, 32, 64)
    RED2(aw); RED2(axl); RED2(ayl); RED2(azl);
    RED2(axx); RED2(ayy); RED2(azz); RED2(axy); RED2(axz); RED2(ayz);
    #undef RED2

    if (g == 0) {
        float l0 = aw * aw;
        float l1 = axl*axl + ayl*ayl + azl*azl;
        float l2 = axx*axx + ayy*ayy + azz*azz + 2.f*(axy*axy + axz*axz + ayz*ayz);
        out[a*48 + k]      = l0;
        out[a*48 + 16 + k] = l1;
        out[a*48 + 32 + k] = l2;
    }
}

// ============ fallback (R1/R4-proven path, minimal workspace) ============

__global__ void hist_kernel(const int* __restrict__ idx0, unsigned* __restrict__ counts, int nneigh) {
    int j = blockIdx.x * blockDim.x + threadIdx.x;
    if (j < nneigh) atomicAdd(&counts[idx0[j]], 1u);
}

__global__ void scan_kernel_1blk(const unsigned* __restrict__ counts, unsigned* __restrict__ offsets,
                                 unsigned* __restrict__ cursor, int nlocal) {
    __shared__ unsigned part[1024];
    int t = threadIdx.x;
    int ch = (nlocal + 1023) / 1024;
    int base = t * ch;
    unsigned s = 0;
    for (int i = 0; i < ch; ++i) { int id = base + i; if (id < nlocal) s += counts[id]; }
    part[t] = s;
    __syncthreads();
    for (int off = 1; off < 1024; off <<= 1) {
        unsigned v = (t >= off) ? part[t - off] : 0u;
        __syncthreads();
        part[t] += v;
        __syncthreads();
    }
    unsigned run = (t == 0) ? 0u : part[t - 1];
    for (int i = 0; i < ch; ++i) {
        int id = base + i;
        if (id < nlocal) { offsets[id] = run; cursor[id] = run; run += counts[id]; }
    }
    if (t == 1023) offsets[nlocal] = part[1023];
}

__global__ __launch_bounds__(256) void scatter_idx(const int* __restrict__ idx0,
                                                   unsigned* __restrict__ cursor,
                                                   unsigned* __restrict__ sorted, int nneigh) {
    int j = blockIdx.x * blockDim.x + threadIdx.x;
    if (j < nneigh) {
        unsigned p = atomicAdd(&cursor[idx0[j]], 1u);
        sorted[p] = (unsigned)j;
    }
}

__global__ __launch_bounds__(256) void density_kernel(
    const float* __restrict__ cart, const float* __restrict__ rs,
    const float* __restrict__ inta, const float* __restrict__ params,
    const int* __restrict__ idx1, const int* __restrict__ nspec,
    const unsigned* __restrict__ offsets, const unsigned* __restrict__ sorted,
    float* __restrict__ out, int nlocal)
{
    int lane = threadIdx.x & 63;
    int a = blockIdx.x * 4 + (threadIdx.x >> 6);
    if (a >= nlocal) return;
    int k = lane & 15;
    int g = lane >> 4;
    float c0x = cart[3*a], c0y = cart[3*a+1], c0z = cart[3*a+2];
    int a1, b1, a2, b2;
    switch (g) {
      case 0:  a1=0; b1=0; a2=1; b2=1; break;
      case 1:  a1=0; b1=1; a2=1; b2=2; break;
      case 2:  a1=0; b1=2; a2=2; b2=0; break;
      default: a1=1; b1=0; a2=2; b2=1; break;
    }
    float acc0 = 0.f, acc1 = 0.f, acc2 = 0.f, acc3 = 0.f;
    unsigned beg = offsets[a], end = offsets[a + 1];
    for (unsigned n = beg; n < end; ++n) {
        int j  = (int)sorted[n];
        int i1 = idx1[j];
        int s  = nspec[j];
        float dxv = c0x - cart[3*i1];
        float dyv = c0y - cart[3*i1+1];
        float dzv = c0z - cart[3*i1+2];
        float d2   = dxv*dxv + dyv*dyv + dzv*dzv;
        float rinv = rsqrtf(d2);
        float dist = d2 * rinv;
        float dx = dxv * rinv, dy = dyv * rinv, dz = dzv * rinv;
        float fc   = 0.5f * __cosf(dist * PI_OVER_CUT) + 0.5f;
        float fcut = fc * fc;
        float tt   = dist - rs[s*NWAVE + k];
        float rad  = __expf(-inta[s*NWAVE + k] * tt * tt) * params[s*NWAVE + k];
        float f1 = (g == 0) ? fcut : fcut * (g == 1 ? dx : (g == 2 ? dy : dz));
        acc0 = fmaf(f1, rad, acc0);
        float pa1 = (a1 == 0 ? dx : (a1 == 1 ? dy : dz));
        float pb1 = (b1 == 0 ? dx : (b1 == 1 ? dy : dz));
        acc1 = fmaf(fcut * pa1 * pb1, rad, acc1);
        float pa2 = (a2 == 0 ? dx : (a2 == 1 ? dy : dz));
        float pb2 = (b2 == 0 ? dx : (b2 == 1 ? dy : dz));
        acc2 = fmaf(fcut * pa2 * pb2, rad, acc2);
        if (g == 0) acc3 = fmaf(fcut * dz * dz, rad, acc3);
    }
    float l0, l1, l2;
    if (g == 0) { l0 = acc0*acc0; l1 = 0.f;        l2 = acc1*acc1 + acc2*acc2 + acc3*acc3; }
    else        { l0 = 0.f;       l1 = acc0*acc0;  l2 = acc1*acc1 + acc2*acc2; }
    l0 += __shfl_xor(l0, 16, 64); l1 += __shfl_xor(l1, 16, 64); l2 += __shfl_xor(l2, 16, 64);
    l0 += __shfl_xor(l0, 32, 64); l1 += __shfl_xor(l1, 32, 64); l2 += __shfl_xor(l2, 32, 64);
    if (g == 0) {
        out[a*48 + k]      = l0;
        out[a*48 + 16 + k] = l1;
        out[a*48 + 32 + k] = l2;
    }
}

// ======================= launch =======================

extern "C" void kernel_launch(void* const* d_in, const int* in_sizes, int n_in,
                              void* d_out, int out_size, void* d_ws, size_t ws_size,
                              hipStream_t stream) {
    const float* cart   = (const float*)d_in[0];
    const float* rs     = (const float*)d_in[1];
    const float* inta   = (const float*)d_in[2];
    const float* params = (const float*)d_in[3];
    const int* atom_index    = (const int*)d_in[4];
    const int* neigh_species = (const int*)d_in[6];
    int nlocal = in_sizes[5];
    int nneigh = in_sizes[6];
    const int* idx0 = atom_index;
    const int* idx1 = atom_index + nneigh;

    int tb = 256;
    int nblkN = (nneigh + tb - 1) / tb;
    int nblkS = (nlocal + 1023) / 1024;
    int nc = (nneigh + CHUNK - 1) >> LOG2CHUNK;
    int halfp = (((nlocal + 1) >> 1) + 63) & ~63;   // padded bins per parity

    char* ws = (char*)d_ws;
    size_t off = 0;
    auto carve = [&](size_t bytes) -> char* {
        off = (off + 255) & ~(size_t)255;
        char* p = ws + off; off += bytes; return p;
    };
    unsigned* counts        = (unsigned*)carve((size_t)nlocal * 4);
    unsigned* offsets       = (unsigned*)carve(((size_t)nlocal + 1) * 4);
    unsigned* cursor        = (unsigned*)carve((size_t)nlocal * 4);
    unsigned* partials      = (unsigned*)carve(256 * 4);
    unsigned* blockoff      = (unsigned*)carve(256 * 4);
    float4*   srec          = (float4*)carve((size_t)nneigh * 16);
    unsigned short* lrank   = (unsigned short*)carve((size_t)nneigh * 2);
    unsigned short* hist16  = (unsigned short*)carve((size_t)nc * 2 * halfp * 2);
    unsigned short* chunkpre= (unsigned short*)carve((size_t)nlocal * nc * 2);
    size_t need_fast = off;

    bool fast = (ws_size >= need_fast) && (nblkS <= 64) && (halfp <= 2 * HIST_WORDS) && (nc <= 64);

    if (fast) {
        chunk_hist_rank<<<nc * 2, 1024, 0, stream>>>(idx0, lrank, hist16, nneigh, halfp);
        combine_pre<<<(nlocal + tb - 1) / tb, tb, 0, stream>>>(hist16, counts, chunkpre,
                                                               nlocal, nc, halfp);
        scan_partial<<<nblkS, 256, 0, stream>>>(counts, partials, nlocal);
        scan_blockoffs<<<1, 64, 0, stream>>>(partials, blockoff, offsets, nblkS, nlocal);
        scan_final<<<nblkS, 256, 0, stream>>>(counts, blockoff, offsets, nlocal);
        geom_scatter_direct<<<nblkN, tb, 0, stream>>>(cart, idx0, idx1, neigh_species,
                                                      lrank, offsets, chunkpre, srec,
                                                      nneigh, nc);
        density_seq<<<(nlocal + 3) / 4, 256, 0, stream>>>(rs, inta, params, offsets, srec,
                                                          (float*)d_out, nlocal, nneigh);
    } else {
        unsigned* sorted = (unsigned*)srec;   // reuse region
        hipMemsetAsync(counts, 0, (size_t)nlocal * 4, stream);
        hist_kernel<<<nblkN, tb, 0, stream>>>(idx0, counts, nneigh);
        scan_kernel_1blk<<<1, 1024, 0, stream>>>(counts, offsets, cursor, nlocal);
        scatter_idx<<<nblkN, tb, 0, stream>>>(idx0, cursor, sorted, nneigh);
        density_kernel<<<(nlocal + 3) / 4, 256, 0, stream>>>(cart, rs, inta, params, idx1,
                                                             neigh_species, offsets, sorted,
                                                             (float*)d_out, nlocal);
    }
}

// Round 7
// 80.172 us; speedup vs baseline: 3.9301x; 1.0619x over previous
//
#include <hip/hip_runtime.h>
#include <hip/hip_bf16.h>

#define NWAVE 16
#define LOG2CHUNK 14
#define CHUNK (1 << LOG2CHUNK)
#define HIST_WORDS 10240   // static LDS: 40KB = 20480 u16 bins (covers nlocal<=40960)

constexpr float PI_OVER_CUT = 3.14159265358979323846f / 5.0f;

// ============ per-chunk LDS histogram + local rank (NO global atomics) ============
// WG bid: chunk c = bid>>1, parity = bid&1. Handles atoms with (a&1)==parity.
// bin = a>>1; u16-packed counts in LDS; lrank[j] = rank within (chunk, atom).

__global__ __launch_bounds__(1024) void chunk_hist_rank(
    const int* __restrict__ idx0, unsigned short* __restrict__ lrank,
    unsigned short* __restrict__ hist16, int nneigh, int halfp)
{
    __shared__ unsigned lds[HIST_WORDS];
    int c = blockIdx.x >> 1;
    int parity = blockIdx.x & 1;
    int t = threadIdx.x;

    int words = halfp >> 1;
    for (int w = t; w < words; w += 1024) lds[w] = 0u;
    __syncthreads();

    int jbeg = c << LOG2CHUNK;
    int jend = jbeg + CHUNK; if (jend > nneigh) jend = nneigh;
    for (int j = jbeg + t; j < jend; j += 1024) {
        int a = idx0[j];
        if ((a & 1) == parity) {
            int bin = a >> 1;
            int word = bin >> 1;
            int shift = (bin & 1) << 4;
            unsigned old = atomicAdd(&lds[word], 1u << shift);
            lrank[j] = (unsigned short)((old >> shift) & 0xffffu);
        }
    }
    __syncthreads();

    unsigned* hrow = (unsigned*)(hist16 + (size_t)blockIdx.x * halfp);
    for (int w = t; w < words; w += 1024) hrow[w] = lds[w];
}

// ============ stage A: per-1024-atom-block aggregate counts ============

__global__ __launch_bounds__(1024) void count_partial(
    const unsigned short* __restrict__ hist16, unsigned* __restrict__ partials,
    int nlocal, int nc, int halfp)
{
    __shared__ unsigned wsum[16];
    int t = threadIdx.x;
    int lane = t & 63, wid = t >> 6;
    int a = blockIdx.x * 1024 + t;
    unsigned v = 0;
    if (a < nlocal) {
        int parity = a & 1, bin = a >> 1;
        for (int c = 0; c < nc; ++c)
            v += hist16[(size_t)(c * 2 + parity) * halfp + bin];
    }
    #pragma unroll
    for (int o = 32; o >= 1; o >>= 1) v += __shfl_xor(v, o, 64);
    if (lane == 0) wsum[wid] = v;
    __syncthreads();
    if (t == 0) {
        unsigned s = 0;
        #pragma unroll
        for (int i = 0; i < 16; ++i) s += wsum[i];
        partials[blockIdx.x] = s;
    }
}

// ============ stage B: offsets + transposed chunk-prefix in one pass ============
// Every block re-scans all block partials (<=64 u32) itself -> no extra dispatch.
// chunkpreT layout [c][a] (padded nlocalp): coalesced writes, L2-hot reads.

__global__ __launch_bounds__(1024) void scan_offsets_chunkpre(
    const unsigned short* __restrict__ hist16, const unsigned* __restrict__ partials,
    unsigned* __restrict__ offsets, unsigned short* __restrict__ chunkpreT,
    int nlocal, int nblk, int nc, int halfp, int nlocalp)
{
    __shared__ unsigned wsum[16];
    __shared__ unsigned sOff;
    int t = threadIdx.x;
    int lane = t & 63, wid = t >> 6;
    int a = blockIdx.x * 1024 + t;

    // wave 0: exclusive scan of the (<=64) block partials -> this block's base
    if (wid == 0) {
        unsigned p = (lane < nblk) ? partials[lane] : 0u;
        unsigned incl = p;
        #pragma unroll
        for (int o = 1; o < 64; o <<= 1) {
            unsigned u = __shfl_up(incl, o, 64);
            if (lane >= o) incl += u;
        }
        if (lane == blockIdx.x) sOff = incl - p;
    }

    // per-atom chunk prefix (transposed write) + per-atom total v
    unsigned v = 0;
    if (a < nlocal) {
        int parity = a & 1, bin = a >> 1;
        for (int c = 0; c < nc; ++c) {
            chunkpreT[(size_t)c * nlocalp + a] = (unsigned short)v;
            v += hist16[(size_t)(c * 2 + parity) * halfp + bin];
        }
    }

    // block-wide exclusive scan of v
    unsigned incl = v;
    #pragma unroll
    for (int o = 1; o < 64; o <<= 1) {
        unsigned u = __shfl_up(incl, o, 64);
        if (lane >= o) incl += u;
    }
    if (lane == 63) wsum[wid] = incl;
    __syncthreads();
    if (t < 16) {
        unsigned u = wsum[t];
        unsigned wincl = u;
        #pragma unroll
        for (int o = 1; o < 16; o <<= 1) {
            unsigned x = __shfl_up(wincl, o, 64);
            if (t >= o) wincl += x;
        }
        wsum[t] = wincl - u;   // exclusive wave prefix
    }
    __syncthreads();
    if (a < nlocal) {
        unsigned o = sOff + wsum[wid] + (incl - v);
        offsets[a] = o;
        if (a == nlocal - 1) offsets[nlocal] = o + v;
    }
}

// ============ fused geometry + atomic-free record scatter ============
// srec[p] = {dx, dy, dz, dist with species in low 2 mantissa bits}, p = sorted pos.

__global__ __launch_bounds__(256) void geom_scatter_direct(
    const float* __restrict__ cart, const int* __restrict__ idx0,
    const int* __restrict__ idx1, const int* __restrict__ nspec,
    const unsigned short* __restrict__ lrank, const unsigned* __restrict__ offsets,
    const unsigned short* __restrict__ chunkpreT, float4* __restrict__ srec,
    int nneigh, int nlocalp)
{
    int j = blockIdx.x * blockDim.x + threadIdx.x;
    if (j >= nneigh) return;
    int i0 = idx0[j], i1 = idx1[j], s = nspec[j];
    int c = j >> LOG2CHUNK;
    unsigned p = offsets[i0] + (unsigned)chunkpreT[(size_t)c * nlocalp + i0]
                             + (unsigned)lrank[j];
    float ax = cart[3*i0], ay = cart[3*i0+1], az = cart[3*i0+2];
    float bx = cart[3*i1], by = cart[3*i1+1], bz = cart[3*i1+2];
    float dxv = ax - bx, dyv = ay - by, dzv = az - bz;
    float d2 = dxv*dxv + dyv*dyv + dzv*dzv;
    float rinv = rsqrtf(d2);
    float dist = d2 * rinv;
    unsigned db = (__float_as_uint(dist) & ~3u) | (unsigned)s;
    srec[p] = make_float4(dxv * rinv, dyv * rinv, dzv * rinv, __uint_as_float(db));
}

// ============ density: one wave per atom, pure streaming reads ============
// lane = g*16+k: group g handles record beg+n+g, channel k. 10 unique sums.

__global__ __launch_bounds__(256) void density_seq(
    const float* __restrict__ rs, const float* __restrict__ inta,
    const float* __restrict__ params, const unsigned* __restrict__ offsets,
    const float4* __restrict__ srec, float* __restrict__ out,
    int nlocal, int nneigh)
{
    int t = threadIdx.x;
    int lane = t & 63;
    int k = lane & 15, g = lane >> 4;
    int a = blockIdx.x * 4 + (t >> 6);
    if (a >= nlocal) return;

    float rs0 = rs[k],        rs1 = rs[16 + k],     rs2 = rs[32 + k],     rs3 = rs[48 + k];
    float ia0 = inta[k],      ia1 = inta[16 + k],   ia2 = inta[32 + k],   ia3 = inta[48 + k];
    float pp0 = params[k],    pp1 = params[16 + k], pp2 = params[32 + k], pp3 = params[48 + k];

    int beg = (int)offsets[a], end = (int)offsets[a + 1];
    int lim = nneigh - 1;

    float aw = 0.f, axl = 0.f, ayl = 0.f, azl = 0.f;
    float axx = 0.f, ayy = 0.f, azz = 0.f, axy = 0.f, axz = 0.f, ayz = 0.f;

    int p0 = beg + g; if (p0 > lim) p0 = lim;
    float4 rec0 = srec[p0];

    for (int n = beg; n < end; n += 4) {
        int p1 = n + 4 + g; if (p1 > lim) p1 = lim;
        float4 rec1 = srec[p1];

        unsigned u = __float_as_uint(rec0.w);
        float dist = __uint_as_float(u & ~3u);
        bool c1 = (u & 1u) != 0u, c2 = (u & 2u) != 0u;
        float rsel = c2 ? (c1 ? rs3 : rs2) : (c1 ? rs1 : rs0);
        float isel = c2 ? (c1 ? ia3 : ia2) : (c1 ? ia1 : ia0);
        float psel = c2 ? (c1 ? pp3 : pp2) : (c1 ? pp1 : pp0);
        float dd  = dist - rsel;
        float rad = __expf(-isel * dd * dd);
        float fc  = fmaf(0.5f, __cosf(dist * PI_OVER_CUT), 0.5f);
        float w   = rad * fc * fc * psel;
        w = (n + g < end) ? w : 0.f;

        float dx = rec0.x, dy = rec0.y, dz = rec0.z;
        float wx = w * dx, wy = w * dy, wz = w * dz;
        aw  += w;
        axl += wx;  ayl += wy;  azl += wz;
        axx = fmaf(wx, dx, axx);  axy = fmaf(wx, dy, axy);  axz = fmaf(wx, dz, axz);
        ayy = fmaf(wy, dy, ayy);  ayz = fmaf(wy, dz, ayz);  azz = fmaf(wz, dz, azz);

        rec0 = rec1;
    }

    #define RED2(x) x += __shfl_xor(x, 16, 64); x += __shfl_xor(x, 32, 64)
    RED2(aw); RED2(axl); RED2(ayl); RED2(azl);
    RED2(axx); RED2(ayy); RED2(azz); RED2(axy); RED2(axz); RED2(ayz);
    #undef RED2

    if (g == 0) {
        float l0 = aw * aw;
        float l1 = axl*axl + ayl*ayl + azl*azl;
        float l2 = axx*axx + ayy*ayy + azz*azz + 2.f*(axy*axy + axz*axz + ayz*ayz);
        out[a*48 + k]      = l0;
        out[a*48 + 16 + k] = l1;
        out[a*48 + 32 + k] = l2;
    }
}

// ============ fallback (R1/R4-proven path, minimal workspace) ============

__global__ void hist_kernel(const int* __restrict__ idx0, unsigned* __restrict__ counts, int nneigh) {
    int j = blockIdx.x * blockDim.x + threadIdx.x;
    if (j < nneigh) atomicAdd(&counts[idx0[j]], 1u);
}

__global__ void scan_kernel_1blk(const unsigned* __restrict__ counts, unsigned* __restrict__ offsets,
                                 unsigned* __restrict__ cursor, int nlocal) {
    __shared__ unsigned part[1024];
    int t = threadIdx.x;
    int ch = (nlocal + 1023) / 1024;
    int base = t * ch;
    unsigned s = 0;
    for (int i = 0; i < ch; ++i) { int id = base + i; if (id < nlocal) s += counts[id]; }
    part[t] = s;
    __syncthreads();
    for (int off = 1; off < 1024; off <<= 1) {
        unsigned v = (t >= off) ? part[t - off] : 0u;
        __syncthreads();
        part[t] += v;
        __syncthreads();
    }
    unsigned run = (t == 0) ? 0u : part[t - 1];
    for (int i = 0; i < ch; ++i) {
        int id = base + i;
        if (id < nlocal) { offsets[id] = run; cursor[id] = run; run += counts[id]; }
    }
    if (t == 1023) offsets[nlocal] = part[1023];
}

__global__ __launch_bounds__(256) void scatter_idx(const int* __restrict__ idx0,
                                                   unsigned* __restrict__ cursor,
                                                   unsigned* __restrict__ sorted, int nneigh) {
    int j = blockIdx.x * blockDim.x + threadIdx.x;
    if (j < nneigh) {
        unsigned p = atomicAdd(&cursor[idx0[j]], 1u);
        sorted[p] = (unsigned)j;
    }
}

__global__ __launch_bounds__(256) void density_kernel(
    const float* __restrict__ cart, const float* __restrict__ rs,
    const float* __restrict__ inta, const float* __restrict__ params,
    const int* __restrict__ idx1, const int* __restrict__ nspec,
    const unsigned* __restrict__ offsets, const unsigned* __restrict__ sorted,
    float* __restrict__ out, int nlocal)
{
    int lane = threadIdx.x & 63;
    int a = blockIdx.x * 4 + (threadIdx.x >> 6);
    if (a >= nlocal) return;
    int k = lane & 15;
    int g = lane >> 4;
    float c0x = cart[3*a], c0y = cart[3*a+1], c0z = cart[3*a+2];
    int a1, b1, a2, b2;
    switch (g) {
      case 0:  a1=0; b1=0; a2=1; b2=1; break;
      case 1:  a1=0; b1=1; a2=1; b2=2; break;
      case 2:  a1=0; b1=2; a2=2; b2=0; break;
      default: a1=1; b1=0; a2=2; b2=1; break;
    }
    float acc0 = 0.f, acc1 = 0.f, acc2 = 0.f, acc3 = 0.f;
    unsigned beg = offsets[a], end = offsets[a + 1];
    for (unsigned n = beg; n < end; ++n) {
        int j  = (int)sorted[n];
        int i1 = idx1[j];
        int s  = nspec[j];
        float dxv = c0x - cart[3*i1];
        float dyv = c0y - cart[3*i1+1];
        float dzv = c0z - cart[3*i1+2];
        float d2   = dxv*dxv + dyv*dyv + dzv*dzv;
        float rinv = rsqrtf(d2);
        float dist = d2 * rinv;
        float dx = dxv * rinv, dy = dyv * rinv, dz = dzv * rinv;
        float fc   = 0.5f * __cosf(dist * PI_OVER_CUT) + 0.5f;
        float fcut = fc * fc;
        float tt   = dist - rs[s*NWAVE + k];
        float rad  = __expf(-inta[s*NWAVE + k] * tt * tt) * params[s*NWAVE + k];
        float f1 = (g == 0) ? fcut : fcut * (g == 1 ? dx : (g == 2 ? dy : dz));
        acc0 = fmaf(f1, rad, acc0);
        float pa1 = (a1 == 0 ? dx : (a1 == 1 ? dy : dz));
        float pb1 = (b1 == 0 ? dx : (b1 == 1 ? dy : dz));
        acc1 = fmaf(fcut * pa1 * pb1, rad, acc1);
        float pa2 = (a2 == 0 ? dx : (a2 == 1 ? dy : dz));
        float pb2 = (b2 == 0 ? dx : (b2 == 1 ? dy : dz));
        acc2 = fmaf(fcut * pa2 * pb2, rad, acc2);
        if (g == 0) acc3 = fmaf(fcut * dz * dz, rad, acc3);
    }
    float l0, l1, l2;
    if (g == 0) { l0 = acc0*acc0; l1 = 0.f;        l2 = acc1*acc1 + acc2*acc2 + acc3*acc3; }
    else        { l0 = 0.f;       l1 = acc0*acc0;  l2 = acc1*acc1 + acc2*acc2; }
    l0 += __shfl_xor(l0, 16, 64); l1 += __shfl_xor(l1, 16, 64); l2 += __shfl_xor(l2, 16, 64);
    l0 += __shfl_xor(l0, 32, 64); l1 += __shfl_xor(l1, 32, 64); l2 += __shfl_xor(l2, 32, 64);
    if (g == 0) {
        out[a*48 + k]      = l0;
        out[a*48 + 16 + k] = l1;
        out[a*48 + 32 + k] = l2;
    }
}

// ======================= launch =======================

extern "C" void kernel_launch(void* const* d_in, const int* in_sizes, int n_in,
                              void* d_out, int out_size, void* d_ws, size_t ws_size,
                              hipStream_t stream) {
    const float* cart   = (const float*)d_in[0];
    const float* rs     = (const float*)d_in[1];
    const float* inta   = (const float*)d_in[2];
    const float* params = (const float*)d_in[3];
    const int* atom_index    = (const int*)d_in[4];
    const int* neigh_species = (const int*)d_in[6];
    int nlocal = in_sizes[5];
    int nneigh = in_sizes[6];
    const int* idx0 = atom_index;
    const int* idx1 = atom_index + nneigh;

    int tb = 256;
    int nblkN = (nneigh + tb - 1) / tb;
    int nc = (nneigh + CHUNK - 1) >> LOG2CHUNK;
    int halfp = (((nlocal + 1) >> 1) + 63) & ~63;   // padded bins per parity
    int nlocalp = (nlocal + 63) & ~63;              // padded atoms (chunkpreT rows)
    int nblkB = (nlocal + 1023) / 1024;             // 1024-atom scan blocks

    char* ws = (char*)d_ws;
    size_t off = 0;
    auto carve = [&](size_t bytes) -> char* {
        off = (off + 255) & ~(size_t)255;
        char* p = ws + off; off += bytes; return p;
    };
    unsigned* counts        = (unsigned*)carve((size_t)nlocal * 4);
    unsigned* offsets       = (unsigned*)carve(((size_t)nlocal + 1) * 4);
    unsigned* cursor        = (unsigned*)carve((size_t)nlocal * 4);
    unsigned* partials      = (unsigned*)carve(256 * 4);
    float4*   srec          = (float4*)carve((size_t)nneigh * 16);
    unsigned short* lrank   = (unsigned short*)carve((size_t)nneigh * 2);
    unsigned short* hist16  = (unsigned short*)carve((size_t)nc * 2 * halfp * 2);
    unsigned short* chunkpreT = (unsigned short*)carve((size_t)nc * nlocalp * 2);
    size_t need_fast = off;

    bool fast = (ws_size >= need_fast) && (nblkB <= 64) &&
                (halfp <= 2 * HIST_WORDS) && (nc <= 64);

    if (fast) {
        chunk_hist_rank<<<nc * 2, 1024, 0, stream>>>(idx0, lrank, hist16, nneigh, halfp);
        count_partial<<<nblkB, 1024, 0, stream>>>(hist16, partials, nlocal, nc, halfp);
        scan_offsets_chunkpre<<<nblkB, 1024, 0, stream>>>(hist16, partials, offsets,
                                                          chunkpreT, nlocal, nblkB, nc,
                                                          halfp, nlocalp);
        geom_scatter_direct<<<nblkN, tb, 0, stream>>>(cart, idx0, idx1, neigh_species,
                                                      lrank, offsets, chunkpreT, srec,
                                                      nneigh, nlocalp);
        density_seq<<<(nlocal + 3) / 4, 256, 0, stream>>>(rs, inta, params, offsets, srec,
                                                          (float*)d_out, nlocal, nneigh);
    } else {
        unsigned* sorted = (unsigned*)srec;   // reuse region
        hipMemsetAsync(counts, 0, (size_t)nlocal * 4, stream);
        hist_kernel<<<nblkN, tb, 0, stream>>>(idx0, counts, nneigh);
        scan_kernel_1blk<<<1, 1024, 0, stream>>>(counts, offsets, cursor, nlocal);
        scatter_idx<<<nblkN, tb, 0, stream>>>(idx0, cursor, sorted, nneigh);
        density_kernel<<<(nlocal + 3) / 4, 256, 0, stream>>>(cart, rs, inta, params, idx1,
                                                             neigh_species, offsets, sorted,
                                                             (float*)d_out, nlocal);
    }
}